// Round 2
// baseline (814.258 us; speedup 1.0000x reference)
//
#include <hip/hip_runtime.h>
#include <hip/hip_bf16.h>

// MultiHeadedAttention with coverage penalty, MI355X/gfx950.
// B=4 L=1024 D=1024 H=16 DK=DV=64. All reference math fp32; we use bf16 MFMA
// (fp32 accum) -- tolerance is 8-ulp bf16 (3.58e-2).
// ws layout (needs 58 MB):
//   [0,8M)       Qb  bf16 [B*H][L][64]   (pre-scaled by 1/8); reused as ctxb later
//   [8,16M)      Kb  bf16 [B*H][L][64]
//   [16,24M)     Vb  bf16 [B*H][L][64]
//   [24,24.25M)  mbuf f32 [B*H*L]        row maxes
//   [24.25,25.25M) Spart f32 [4][B*H][L] partial rowsums per column block
//   [25.25M)     flag int                mask dtype mode
//   [26,58M)     Cpart bf16 [4][B*H][L][64] partial contexts
//   ctxb bf16 [B][L][H*64] = Qb region (Qb dead after attn_kernel)

typedef unsigned short u16;
typedef __bf16 v8bf __attribute__((ext_vector_type(8)));
typedef u16    v8us __attribute__((ext_vector_type(8)));
typedef float  v4f  __attribute__((ext_vector_type(4)));

__device__ __forceinline__ u16 f2b(float f){
  __hip_bfloat16 h = __float2bfloat16(f);
  return __builtin_bit_cast(u16, h);
}
__device__ __forceinline__ float b2f(u16 u){
  __hip_bfloat16 h = __builtin_bit_cast(__hip_bfloat16, u);
  return __bfloat162float(h);
}

// mask dtype modes: 0 = 1-byte bool, 1 = int32, 2 = float32, 3 = bf16
__device__ __forceinline__ bool mask_at(const void* m, int mode, size_t idx){
  if (mode == 0) return ((const unsigned char*)m)[idx] != 0;
  if (mode == 1) return ((const int*)m)[idx] != 0;
  if (mode == 3) return ((const u16*)m)[idx] != 0;
  return ((const float*)m)[idx] != 0.0f;
}

// Classify the mask buffer's dtype from its byte pattern (values are only 0/1).
// bool bytes: nonzero bytes at non-word-aligned offsets, never 0x3f pattern.
// int32 0/1: bytes 1..3 of each word always zero.
// f32 1.0f = [00 00 80 3f] -> byte3==0x3f.  bf16 1.0 = [80 3f] -> byte1==0x3f.
__global__ void detect_kernel(const unsigned int* __restrict__ m, int* __restrict__ flag){
  __shared__ int sb1, sb3, snz;
  int tid = threadIdx.x;
  if (tid == 0){ sb1 = 0; sb3 = 0; snz = 0; }
  __syncthreads();
  int l1 = 0, l3 = 0, ln = 0;
  for (int i = tid; i < 65536; i += 256){
    unsigned v = m[i];
    unsigned b1 = (v >> 8) & 0xffu, b2 = (v >> 16) & 0xffu, b3 = (v >> 24) & 0xffu;
    l1 |= (b1 == 0x3fu);
    l3 |= (b3 == 0x3fu);
    ln |= ((b1 | b2 | b3) != 0u);
  }
  if (l1) atomicOr(&sb1, 1);
  if (l3) atomicOr(&sb3, 1);
  if (ln) atomicOr(&snz, 1);
  __syncthreads();
  if (tid == 0) *flag = sb1 ? 3 : (sb3 ? 2 : (snz ? 0 : 1));
}

// C = A(4096x1024) @ W(1024x1024) + bias, bf16 MFMA 16x16x32, 128x128 tile.
// AMODE 0: A fp32 (cast on stage); 1: A bf16.
// OMODE 0: scatter bf16 to [B*H][L][64] with (acc+bias)*scale; 1: fp32 to out[r*1024+c].
template<int AMODE, int OMODE>
__global__ __launch_bounds__(256)
void gemm_kernel(const void* __restrict__ Aptr, const float* __restrict__ W,
                 const float* __restrict__ bias, float scale, void* __restrict__ outp)
{
  __shared__ alignas(16) u16 As[128][40];   // [row][k], +8 pad
  __shared__ alignas(16) u16 Bs[128][40];   // [col][k] (W transposed), +8 pad
  const int tid = threadIdx.x;
  const int l = tid & 63, w = tid >> 6;
  const int li = l & 15, g = l >> 4;
  const int rowBase = blockIdx.y * 128;
  const int colBase = blockIdx.x * 128;
  const int wm = w >> 1, wn = w & 1;

  v4f acc[4][4];
  #pragma unroll
  for (int i = 0; i < 4; i++)
    #pragma unroll
    for (int j = 0; j < 4; j++) acc[i][j] = (v4f){0.f, 0.f, 0.f, 0.f};

  const int sr  = tid >> 1;         // 0..127 (A row / W col)
  const int skh = (tid & 1) * 16;   // k half

  for (int kt = 0; kt < 32; ++kt){
    const int k0 = kt * 32;
    __syncthreads();
    { // stage A tile (128x32) as bf16
      v8us p0, p1;
      if (AMODE == 0){
        const float* A = (const float*)Aptr;
        const float* src = &A[(size_t)(rowBase + sr) * 1024 + k0 + skh];
        float xs[16];
        #pragma unroll
        for (int i = 0; i < 4; i++){
          float4 f = ((const float4*)src)[i];
          xs[4*i+0] = f.x; xs[4*i+1] = f.y; xs[4*i+2] = f.z; xs[4*i+3] = f.w;
        }
        #pragma unroll
        for (int i = 0; i < 8; i++){ p0[i] = f2b(xs[i]); p1[i] = f2b(xs[8+i]); }
      } else {
        const u16* A = (const u16*)Aptr;
        const v8us* src = (const v8us*)&A[(size_t)(rowBase + sr) * 1024 + k0 + skh];
        p0 = src[0]; p1 = src[1];
      }
      *(v8us*)&As[sr][skh]     = p0;
      *(v8us*)&As[sr][skh + 8] = p1;
    }
    { // stage W tile (32x128) transposed -> Bs[col][k]
      v8us p0, p1;
      #pragma unroll
      for (int i = 0; i < 8; i++){
        p0[i] = f2b(W[(size_t)(k0 + skh + i)     * 1024 + colBase + sr]);
        p1[i] = f2b(W[(size_t)(k0 + skh + 8 + i) * 1024 + colBase + sr]);
      }
      *(v8us*)&Bs[sr][skh]     = p0;
      *(v8us*)&Bs[sr][skh + 8] = p1;
    }
    __syncthreads();
    v8bf af[4], bf[4];
    #pragma unroll
    for (int mt = 0; mt < 4; ++mt)
      af[mt] = *(const v8bf*)&As[wm*64 + mt*16 + li][g*8];
    #pragma unroll
    for (int nt = 0; nt < 4; ++nt)
      bf[nt] = *(const v8bf*)&Bs[wn*64 + nt*16 + li][g*8];
    #pragma unroll
    for (int mt = 0; mt < 4; ++mt)
      #pragma unroll
      for (int nt = 0; nt < 4; ++nt)
        acc[mt][nt] = __builtin_amdgcn_mfma_f32_16x16x32_bf16(af[mt], bf[nt], acc[mt][nt], 0, 0, 0);
  }

  #pragma unroll
  for (int mt = 0; mt < 4; ++mt){
    #pragma unroll
    for (int nt = 0; nt < 4; ++nt){
      const int gc = colBase + wn*64 + nt*16 + li;
      const float bs = bias[gc];
      #pragma unroll
      for (int r = 0; r < 4; ++r){
        const int gr = rowBase + wm*64 + mt*16 + g*4 + r;
        float v = acc[mt][nt][r] + bs;
        if (OMODE == 0){
          v *= scale;
          const int bb = gr >> 10, lp = gr & 1023;
          const int h = gc >> 6, dk = gc & 63;
          ((u16*)outp)[((((size_t)bb*16 + h) << 10) + lp) * 64 + dk] = f2b(v);
        } else {
          ((float*)outp)[(size_t)gr * 1024 + gc] = v;
        }
      }
    }
  }
}

// Row maxes of masked scores. grid = B*H*16, block 256 (4 waves x 16 q-rows).
__global__ __launch_bounds__(256)
void rowmax_kernel(const u16* __restrict__ Qb, const u16* __restrict__ Kb,
                   const void* __restrict__ mask, const int* __restrict__ modep,
                   float* __restrict__ mbuf)
{
  const int tid = threadIdx.x, l = tid & 63, w = tid >> 6;
  const int li = l & 15, g = l >> 4;
  const int bid = blockIdx.x;
  const int bh = bid >> 4, qb = bid & 15;
  const int b = bh >> 4;
  const int mode = *modep;
  const int qrow0 = qb * 64 + w * 16;

  const u16* qbase = &Qb[((size_t)bh * 1024 + qrow0 + li) * 64 + g * 8];
  const v8bf a0 = *(const v8bf*)qbase;
  const v8bf a1 = *(const v8bf*)(qbase + 32);

  float rm[4] = {-3.0e38f, -3.0e38f, -3.0e38f, -3.0e38f};
  const size_t mb = ((size_t)b << 20);

  for (int kt = 0; kt < 64; ++kt){
    const u16* kbase = &Kb[((size_t)bh * 1024 + kt*16 + li) * 64 + g * 8];
    v8bf b0 = *(const v8bf*)kbase;
    v8bf b1 = *(const v8bf*)(kbase + 32);
    v4f s = (v4f){0.f, 0.f, 0.f, 0.f};
    s = __builtin_amdgcn_mfma_f32_16x16x32_bf16(a0, b0, s, 0, 0, 0);
    s = __builtin_amdgcn_mfma_f32_16x16x32_bf16(a1, b1, s, 0, 0, 0);
    const int col = kt * 16 + li;
    #pragma unroll
    for (int r = 0; r < 4; ++r){
      const int row = qrow0 + g*4 + r;
      const bool mk = mask_at(mask, mode, mb + ((size_t)row << 10) + col);
      const float sv = mk ? -1e18f : s[r];
      rm[r] = fmaxf(rm[r], sv);
    }
  }
  #pragma unroll
  for (int r = 0; r < 4; ++r){
    float v = rm[r];
    v = fmaxf(v, __shfl_xor(v, 1));
    v = fmaxf(v, __shfl_xor(v, 2));
    v = fmaxf(v, __shfl_xor(v, 4));
    v = fmaxf(v, __shfl_xor(v, 8));
    rm[r] = v;
  }
  if (li == 0){
    #pragma unroll
    for (int r = 0; r < 4; ++r)
      mbuf[(size_t)bh * 1024 + qrow0 + g*4 + r] = rm[r];
  }
}

// Coverage-penalty attention, partial over a 256-column block.
// grid = B*H*4 (kb column blocks), block 512 (8 waves x 16 rows = 128-row chunks).
__global__ __launch_bounds__(512)
void attn_kernel(const u16* __restrict__ Qb, const u16* __restrict__ Kb,
                 const u16* __restrict__ Vb, const void* __restrict__ mask,
                 const int* __restrict__ modep, const float* __restrict__ mbuf,
                 float* __restrict__ Spart, u16* __restrict__ Cpart)
{
  __shared__ alignas(16) u16 Vt[64][264];        // V^T for this column block
  __shared__ alignas(16) u16 Ulds[8][16][264];   // per-wave u rows (bf16)
  __shared__ float Cc[256];                      // cross-chunk column carry
  __shared__ float Tw[8][256];                   // per-wave chunk column totals

  const int tid = threadIdx.x, l = tid & 63, w = tid >> 6;
  const int li = l & 15, g = l >> 4;
  const int bid = blockIdx.x;
  const int bh = bid >> 2, kb = bid & 3;
  const int b = bh >> 4;
  const int mode = *modep;
  const int col0 = kb * 256;

  for (int idx = tid; idx < 256 * 64; idx += 512){
    const int k = idx >> 6, dv = idx & 63;
    Vt[dv][k] = Vb[((size_t)bh * 1024 + col0 + k) * 64 + dv];
  }
  if (tid < 256) Cc[tid] = 0.f;
  __syncthreads();

  for (int qc = 0; qc < 8; ++qc){
    const int qw0 = qc * 128 + w * 16;
    const u16* qbase = &Qb[((size_t)bh * 1024 + qw0 + li) * 64 + g * 8];
    const v8bf a0 = *(const v8bf*)qbase;
    const v8bf a1 = *(const v8bf*)(qbase + 32);

    // scores for 16 rows x 256 cols
    v4f sc[16];
    #pragma unroll
    for (int nt = 0; nt < 16; ++nt){
      const u16* kbase = &Kb[((size_t)bh * 1024 + col0 + nt*16 + li) * 64 + g * 8];
      v8bf b0 = *(const v8bf*)kbase;
      v8bf b1 = *(const v8bf*)(kbase + 32);
      v4f s = (v4f){0.f, 0.f, 0.f, 0.f};
      s = __builtin_amdgcn_mfma_f32_16x16x32_bf16(a0, b0, s, 0, 0, 0);
      s = __builtin_amdgcn_mfma_f32_16x16x32_bf16(a1, b1, s, 0, 0, 0);
      sc[nt] = s;
    }
    float mrow[4];
    #pragma unroll
    for (int r = 0; r < 4; ++r) mrow[r] = mbuf[(size_t)bh * 1024 + qw0 + g*4 + r];

    // exp + column totals over this wave's 16 rows
    float tot[16];
    #pragma unroll
    for (int nt = 0; nt < 16; ++nt){
      const int col = col0 + nt*16 + li;
      const size_t mbase = ((size_t)b << 20) + col;
      float t = 0.f;
      #pragma unroll
      for (int r = 0; r < 4; ++r){
        const int row = qw0 + g*4 + r;
        const bool mk = mask_at(mask, mode, mbase + ((size_t)row << 10));
        const float e = mk ? 0.f : __expf(sc[nt][r] - mrow[r]);
        sc[nt][r] = e;
        t += e;
      }
      tot[nt] = t;
    }
    // cross-lane-group exclusive carry within the wave; wave totals to LDS
    float cg[16];
    #pragma unroll
    for (int nt = 0; nt < 16; ++nt){
      const float t  = tot[nt];
      const float t1 = __shfl_up(t, 16);
      const float t2 = __shfl_up(t, 32);
      const float t3 = __shfl_up(t, 48);
      float c = 0.f;
      if (g >= 1) c += t1;
      if (g >= 2) c += t2;
      if (g >= 3) c += t3;
      cg[nt] = c;
      if (g == 3) Tw[w][nt*16 + li] = c + t;
    }
    __syncthreads();

    // penalties -> u -> Ulds(bf16) + rowsums
    float rs[4] = {0.f, 0.f, 0.f, 0.f};
    #pragma unroll
    for (int nt = 0; nt < 16; ++nt){
      const int c = nt*16 + li;
      float base = Cc[c];
      #pragma unroll
      for (int ww = 0; ww < 7; ++ww) if (w > ww) base += Tw[ww][c];
      float run = 0.f;
      #pragma unroll
      for (int r = 0; r < 4; ++r){
        const int Rg = qc*128 + w*16 + g*4 + r;     // global q row
        float pen = base + cg[nt] + run;
        if (Rg == 0) pen = 1.0f;                    // penalty[0] = 1
        const float e = sc[nt][r];
        const float u = e / (pen + 1e-8f);
        run += e;
        rs[r] += u;
        Ulds[w][g*4 + r][c] = f2b(u);
      }
    }
    #pragma unroll
    for (int r = 0; r < 4; ++r){
      float v = rs[r];
      v += __shfl_xor(v, 1);
      v += __shfl_xor(v, 2);
      v += __shfl_xor(v, 4);
      v += __shfl_xor(v, 8);
      rs[r] = v;
    }
    if (li == 0){
      #pragma unroll
      for (int r = 0; r < 4; ++r)
        Spart[(((size_t)kb*64 + bh) << 10) + qw0 + g*4 + r] = rs[r];
    }
    __syncthreads();
    if (tid < 256){
      Cc[tid] += Tw[0][tid] + Tw[1][tid] + Tw[2][tid] + Tw[3][tid]
               + Tw[4][tid] + Tw[5][tid] + Tw[6][tid] + Tw[7][tid];
    }
    __syncthreads();

    // PV: (16 x 256) @ (256 x 64)
    v4f pv[4];
    #pragma unroll
    for (int n = 0; n < 4; ++n) pv[n] = (v4f){0.f, 0.f, 0.f, 0.f};
    #pragma unroll
    for (int kk = 0; kk < 8; ++kk){
      v8bf ua = *(const v8bf*)&Ulds[w][li][g*8 + kk*32];
      #pragma unroll
      for (int n = 0; n < 4; ++n){
        v8bf vb = *(const v8bf*)&Vt[n*16 + li][g*8 + kk*32];
        pv[n] = __builtin_amdgcn_mfma_f32_16x16x32_bf16(ua, vb, pv[n], 0, 0, 0);
      }
    }
    #pragma unroll
    for (int n = 0; n < 4; ++n){
      #pragma unroll
      for (int r = 0; r < 4; ++r){
        const int row = qw0 + g*4 + r;
        const int dv = n*16 + li;
        Cpart[((((size_t)kb*64 + bh) << 10) + row) * 64 + dv] = f2b(pv[n][r]);
      }
    }
  }
}

// Merge column-block partials: ctx = sum(Cpart)/sum(Spart), relayout to (B,L,H*64) bf16.
__global__ __launch_bounds__(256)
void reduce_kernel(const u16* __restrict__ Cpart, const float* __restrict__ Spart,
                   u16* __restrict__ ctxb)
{
  const size_t idx = (size_t)blockIdx.x * 256 + threadIdx.x;  // < 4M
  const int dv = (int)(idx & 63);
  const int q  = (int)((idx >> 6) & 1023);
  const int bh = (int)(idx >> 16);
  float s = 0.f, c = 0.f;
  #pragma unroll
  for (int kb = 0; kb < 4; ++kb){
    const size_t r = (size_t)kb * 65536 + ((size_t)bh << 10) + q;
    s += Spart[r];
    c += b2f(Cpart[r * 64 + dv]);
  }
  const float val = c / s;
  const int b = bh >> 4, h = bh & 15;
  ctxb[((((size_t)b << 10) + q) * 16 + h) * 64 + dv] = f2b(val);
}

extern "C" void kernel_launch(void* const* d_in, const int* in_sizes, int n_in,
                              void* d_out, int out_size, void* d_ws, size_t ws_size,
                              hipStream_t stream)
{
  const float* key   = (const float*)d_in[0];
  const float* value = (const float*)d_in[1];
  const float* query = (const float*)d_in[2];
  const void*  mask  = d_in[3];
  const float* Wq = (const float*)d_in[4];
  const float* bq = (const float*)d_in[5];
  const float* Wk = (const float*)d_in[6];
  const float* bk = (const float*)d_in[7];
  const float* Wv = (const float*)d_in[8];
  const float* bv = (const float*)d_in[9];
  const float* Wo = (const float*)d_in[10];
  const float* bo = (const float*)d_in[11];

  if (ws_size < (58ull << 20)) return;  // need 58 MB scratch

  char* ws = (char*)d_ws;
  u16*   Qb    = (u16*)(ws);
  u16*   Kb    = (u16*)(ws + (8ull  << 20));
  u16*   Vb    = (u16*)(ws + (16ull << 20));
  float* mbuf  = (float*)(ws + (24ull << 20));
  float* Spart = (float*)(ws + (24ull << 20) + (256u << 10));
  int*   flag  = (int*)  (ws + (25ull << 20) + (256u << 10));
  u16*   Cpart = (u16*)(ws + (26ull << 20));
  u16*   ctxb  = (u16*)(ws);  // reuse Qb region (dead after attn_kernel)

  detect_kernel<<<1, 256, 0, stream>>>((const unsigned int*)mask, flag);

  dim3 gg(8, 32);
  gemm_kernel<0,0><<<gg, 256, 0, stream>>>(query, Wq, bq, 0.125f, Qb);
  gemm_kernel<0,0><<<gg, 256, 0, stream>>>(key,   Wk, bk, 1.0f,   Kb);
  gemm_kernel<0,0><<<gg, 256, 0, stream>>>(value, Wv, bv, 1.0f,   Vb);

  rowmax_kernel<<<1024, 256, 0, stream>>>(Qb, Kb, mask, flag, mbuf);
  attn_kernel<<<256, 512, 0, stream>>>(Qb, Kb, Vb, mask, flag, mbuf, Spart, Cpart);
  reduce_kernel<<<16384, 256, 0, stream>>>(Cpart, Spart, ctxb);

  gemm_kernel<1,1><<<gg, 256, 0, stream>>>(ctxb, Wo, bo, 1.0f, d_out);
}

// Round 4
// 541.483 us; speedup vs baseline: 1.5038x; 1.5038x over previous
//
#include <hip/hip_runtime.h>
#include <hip/hip_bf16.h>

// MultiHeadedAttention with coverage penalty, MI355X/gfx950.
// B=4 L=1024 D=1024 H=16 DK=DV=64. bf16 MFMA, fp32 accum; tol 3.58e-2.
//
// Structure (v3): prep (detect+bitmask+casts+W-transpose) -> 3 proj GEMMs ->
// rowmax -> colsum(pass1, per-chunk column sums) -> scan (exclusive chunk
// carry) -> attn2(pass2: recompute QK, penalty via carry, PV accumulated over
// all 4 col-blocks, writes normalized context) -> output GEMM.
//
// ws layout (57 MB used; guard 58 MB as in the passing r2 build):
//   0M:   Qb   bf16 [B*H][L][64]  (Q/8)
//   8M:   Kb   bf16 [B*H][L][64]
//   16M:  Vb   bf16 [B*H][L][64]
//   24M:  Ac   bf16 [4096][1024]  shared cast buffer (serially reused Q,K,V)
//   32M:  ctxb bf16 [B][L][H*64]
//   40M:  Wt   bf16 4 x [1024][1024] pre-transposed weights (2M each)
//   48M:  mbuf f32 [B*H*L] row maxes (256K)
//   48.25M: bm  u32 bitmask [B][L][32] (512K)
//   48.75M: flag int (mask dtype mode)
//   49M:  Tsum f32 [B*H][16][1024] chunk column sums (4M)
//   53M:  Cscan f32 [B*H][16][1024] exclusive scan of Tsum (4M)

typedef unsigned short u16;
typedef unsigned int u32;
typedef __bf16 v8bf __attribute__((ext_vector_type(8)));
typedef u16    v8us __attribute__((ext_vector_type(8)));
typedef float  v4f  __attribute__((ext_vector_type(4)));

__device__ __forceinline__ u16 f2b(float f){
  __hip_bfloat16 h = __float2bfloat16(f);
  return __builtin_bit_cast(u16, h);
}

// ---------- mask dtype detect (0=bool byte, 1=int32, 2=f32, 3=bf16) ----------
__global__ void detect_kernel(const u32* __restrict__ m, int* __restrict__ flag){
  __shared__ int sb1, sb3, snz;
  int tid = threadIdx.x;
  if (tid == 0){ sb1 = 0; sb3 = 0; snz = 0; }
  __syncthreads();
  int l1 = 0, l3 = 0, ln = 0;
  for (int i = tid; i < 65536; i += 256){
    u32 v = m[i];
    u32 b1 = (v >> 8) & 0xffu, b2 = (v >> 16) & 0xffu, b3 = (v >> 24) & 0xffu;
    l1 |= (b1 == 0x3fu);
    l3 |= (b3 == 0x3fu);
    ln |= ((b1 | b2 | b3) != 0u);
  }
  if (l1) atomicOr(&sb1, 1);
  if (l3) atomicOr(&sb3, 1);
  if (ln) atomicOr(&snz, 1);
  __syncthreads();
  if (tid == 0) *flag = sb1 ? 3 : (sb3 ? 2 : (snz ? 0 : 1));
}

// ---------- pack mask into bits: bm[(b*1024+row)*32 + w], bit = col&31 ------
__global__ __launch_bounds__(256)
void pack_mask(const void* __restrict__ m, const int* __restrict__ modep,
               u32* __restrict__ bm)
{
  const int w = blockIdx.x * 256 + threadIdx.x;   // 0..131071 global word
  const int mode = *modep;
  u32 out = 0;
  if (mode == 0){
    const u32* p = (const u32*)m + (size_t)w * 8;
    #pragma unroll
    for (int i = 0; i < 8; i++){
      u32 v = p[i];
      if (v & 0x000000ffu) out |= 1u << (4*i+0);
      if (v & 0x0000ff00u) out |= 1u << (4*i+1);
      if (v & 0x00ff0000u) out |= 1u << (4*i+2);
      if (v & 0xff000000u) out |= 1u << (4*i+3);
    }
  } else if (mode == 3){
    const u16* p = (const u16*)m + (size_t)w * 32;
    for (int i = 0; i < 32; i++) if (p[i]) out |= 1u << i;
  } else {
    const u32* p = (const u32*)m + (size_t)w * 32;
    for (int i = 0; i < 32; i++) if (p[i]) out |= 1u << i;
  }
  bm[w] = out;
}

// ---------- fp32 -> bf16 flat cast (vector8) --------------------------------
__global__ __launch_bounds__(256)
void cast_bf16(const float* __restrict__ in, u16* __restrict__ out){
  const int i = blockIdx.x * 256 + threadIdx.x;   // 0..524287 (x8 elements)
  const float4* p = (const float4*)(in + (size_t)i * 8);
  float4 a = p[0], b = p[1];
  v8us r;
  r[0]=f2b(a.x); r[1]=f2b(a.y); r[2]=f2b(a.z); r[3]=f2b(a.w);
  r[4]=f2b(b.x); r[5]=f2b(b.y); r[6]=f2b(b.z); r[7]=f2b(b.w);
  ((v8us*)out)[i] = r;
}

// ---------- W [k][n] f32 -> Wt [n][k] bf16, 64x64 LDS tiles -----------------
__global__ __launch_bounds__(256)
void transpose_cast(const float* __restrict__ W, u16* __restrict__ Wt){
  __shared__ float T[64][65];
  const int ki = blockIdx.y, ni = blockIdx.x, t = threadIdx.x;
  const int r = t >> 2, c4 = (t & 3) * 16;
  const float4* src = (const float4*)&W[(size_t)(ki*64 + r) * 1024 + ni*64 + c4];
  #pragma unroll
  for (int i = 0; i < 4; i++){
    float4 f = src[i];
    T[r][c4+4*i+0]=f.x; T[r][c4+4*i+1]=f.y; T[r][c4+4*i+2]=f.z; T[r][c4+4*i+3]=f.w;
  }
  __syncthreads();
  u16* dst = &Wt[(size_t)(ni*64 + r) * 1024 + ki*64 + c4];
  v8us o0, o1;
  #pragma unroll
  for (int j = 0; j < 8; j++){ o0[j] = f2b(T[c4+j][r]); o1[j] = f2b(T[c4+8+j][r]); }
  *(v8us*)dst = o0;
  *(v8us*)(dst + 8) = o1;
}

// ---------- GEMM: A bf16 [4096][1024] @ Wt^T + bias. Tile 128x64, BK=64 -----
// OMODE 0: scatter bf16 (acc+bias)*scale to [B*H][L][64]; 1: fp32 row-major.
template<int OMODE>
__global__ __launch_bounds__(256)
void gemm_bf16(const u16* __restrict__ A, const u16* __restrict__ Wt,
               const float* __restrict__ bias, float scale, void* __restrict__ outp)
{
  __shared__ alignas(16) u16 As[128][72];
  __shared__ alignas(16) u16 Bs[64][72];
  const int tid = threadIdx.x, l = tid & 63, w = tid >> 6;
  const int li = l & 15, g = l >> 4;
  const int rowBase = blockIdx.y * 128, colBase = blockIdx.x * 64;

  v4f acc[2][4];
  #pragma unroll
  for (int i = 0; i < 2; i++)
    #pragma unroll
    for (int j = 0; j < 4; j++) acc[i][j] = (v4f){0.f,0.f,0.f,0.f};

  const int ar = tid >> 1, ak = (tid & 1) * 32;   // A: 4 v8us
  const int br = tid >> 2, bk = (tid & 3) * 16;   // B: 2 v8us

  for (int kt = 0; kt < 16; ++kt){
    const int k0 = kt * 64;
    __syncthreads();
    {
      const v8us* as = (const v8us*)&A[(size_t)(rowBase + ar) * 1024 + k0 + ak];
      v8us a0 = as[0], a1 = as[1], a2 = as[2], a3 = as[3];
      *(v8us*)&As[ar][ak]      = a0;
      *(v8us*)&As[ar][ak + 8]  = a1;
      *(v8us*)&As[ar][ak + 16] = a2;
      *(v8us*)&As[ar][ak + 24] = a3;
      const v8us* bs = (const v8us*)&Wt[(size_t)(colBase + br) * 1024 + k0 + bk];
      v8us b0 = bs[0], b1 = bs[1];
      *(v8us*)&Bs[br][bk]     = b0;
      *(v8us*)&Bs[br][bk + 8] = b1;
    }
    __syncthreads();
    #pragma unroll
    for (int kk = 0; kk < 2; ++kk){
      v8bf af[2], bf[4];
      #pragma unroll
      for (int mt = 0; mt < 2; ++mt)
        af[mt] = *(const v8bf*)&As[w*32 + mt*16 + li][kk*32 + g*8];
      #pragma unroll
      for (int nt = 0; nt < 4; ++nt)
        bf[nt] = *(const v8bf*)&Bs[nt*16 + li][kk*32 + g*8];
      #pragma unroll
      for (int mt = 0; mt < 2; ++mt)
        #pragma unroll
        for (int nt = 0; nt < 4; ++nt)
          acc[mt][nt] = __builtin_amdgcn_mfma_f32_16x16x32_bf16(af[mt], bf[nt], acc[mt][nt], 0, 0, 0);
    }
  }

  #pragma unroll
  for (int mt = 0; mt < 2; ++mt){
    #pragma unroll
    for (int nt = 0; nt < 4; ++nt){
      const int gc = colBase + nt*16 + li;
      const float bs = bias[gc];
      #pragma unroll
      for (int r = 0; r < 4; ++r){
        const int gr = rowBase + w*32 + mt*16 + g*4 + r;
        float v = acc[mt][nt][r] + bs;
        if (OMODE == 0){
          v *= scale;
          const int bb = gr >> 10, lp = gr & 1023;
          const int h = gc >> 6, dk = gc & 63;
          ((u16*)outp)[((((size_t)bb*16 + h) << 10) + lp) * 64 + dk] = f2b(v);
        } else {
          ((float*)outp)[(size_t)gr * 1024 + gc] = v;
        }
      }
    }
  }
}

// ---------- row maxes of masked scores. grid B*H*16, 4 waves x 16 rows ------
__global__ __launch_bounds__(256)
void rowmax_kernel(const u16* __restrict__ Qb, const u16* __restrict__ Kb,
                   const u32* __restrict__ bm, float* __restrict__ mbuf)
{
  const int tid = threadIdx.x, l = tid & 63, w = tid >> 6;
  const int li = l & 15, g = l >> 4;
  const int bid = blockIdx.x;
  const int bh = bid >> 4, qb = bid & 15;
  const int b = bh >> 4;
  const int qrow0 = qb * 64 + w * 16;
  const u32* bmb = bm + ((size_t)b << 15);

  const u16* qbase = &Qb[((size_t)bh * 1024 + qrow0 + li) * 64 + g * 8];
  const v8bf a0 = *(const v8bf*)qbase;
  const v8bf a1 = *(const v8bf*)(qbase + 32);

  float rm[4] = {-3.0e38f, -3.0e38f, -3.0e38f, -3.0e38f};

  for (int kt = 0; kt < 64; ++kt){
    const u16* kbase = &Kb[((size_t)bh * 1024 + kt*16 + li) * 64 + g * 8];
    v8bf b0 = *(const v8bf*)kbase;
    v8bf b1 = *(const v8bf*)(kbase + 32);
    v4f s = (v4f){0.f,0.f,0.f,0.f};
    s = __builtin_amdgcn_mfma_f32_16x16x32_bf16(a0, b0, s, 0, 0, 0);
    s = __builtin_amdgcn_mfma_f32_16x16x32_bf16(a1, b1, s, 0, 0, 0);
    const int bit = ((kt & 1) << 4) + li;
    #pragma unroll
    for (int r = 0; r < 4; ++r){
      const int row = qrow0 + g*4 + r;
      const u32 mw = bmb[(row << 5) | (kt >> 1)];
      const float sv = ((mw >> bit) & 1u) ? -1e18f : s[r];
      rm[r] = fmaxf(rm[r], sv);
    }
  }
  #pragma unroll
  for (int r = 0; r < 4; ++r){
    float v = rm[r];
    v = fmaxf(v, __shfl_xor(v, 1));
    v = fmaxf(v, __shfl_xor(v, 2));
    v = fmaxf(v, __shfl_xor(v, 4));
    v = fmaxf(v, __shfl_xor(v, 8));
    rm[r] = v;
  }
  if (li == 0){
    #pragma unroll
    for (int r = 0; r < 4; ++r)
      mbuf[(size_t)bh * 1024 + qrow0 + g*4 + r] = rm[r];
  }
}

// ---------- pass1: per-chunk (64 rows) column sums of e ---------------------
// grid = B*H * 16 chunks * 4 colblocks = 4096 WGs, 4 waves x 16 rows.
__global__ __launch_bounds__(256)
void colsum_kernel(const u16* __restrict__ Qb, const u16* __restrict__ Kb,
                   const u32* __restrict__ bm, const float* __restrict__ mbuf,
                   float* __restrict__ Tsum)
{
  __shared__ float Tw[4][256];
  const int tid = threadIdx.x, l = tid & 63, w = tid >> 6;
  const int li = l & 15, g = l >> 4;
  const int bid = blockIdx.x;
  const int bh = bid >> 6, qc = (bid >> 2) & 15, kb = bid & 3;
  const int b = bh >> 4;
  const int col0 = kb * 256;
  const int qrow0 = qc * 64 + w * 16;
  const u32* bmb = bm + ((size_t)b << 15);

  const u16* qbase = &Qb[((size_t)bh * 1024 + qrow0 + li) * 64 + g * 8];
  const v8bf a0 = *(const v8bf*)qbase;
  const v8bf a1 = *(const v8bf*)(qbase + 32);
  float mrow[4];
  #pragma unroll
  for (int r = 0; r < 4; ++r) mrow[r] = mbuf[(size_t)bh * 1024 + qrow0 + g*4 + r];

  #pragma unroll
  for (int nt = 0; nt < 16; ++nt){
    const u16* kbase = &Kb[((size_t)bh * 1024 + col0 + nt*16 + li) * 64 + g * 8];
    v8bf b0 = *(const v8bf*)kbase;
    v8bf b1 = *(const v8bf*)(kbase + 32);
    v4f s = (v4f){0.f,0.f,0.f,0.f};
    s = __builtin_amdgcn_mfma_f32_16x16x32_bf16(a0, b0, s, 0, 0, 0);
    s = __builtin_amdgcn_mfma_f32_16x16x32_bf16(a1, b1, s, 0, 0, 0);
    const int wi = (col0 >> 5) + (nt >> 1);
    const int bit = ((nt & 1) << 4) + li;
    float t = 0.f;
    #pragma unroll
    for (int r = 0; r < 4; ++r){
      const int row = qrow0 + g*4 + r;
      const u32 mw = bmb[(row << 5) | wi];
      const float e = ((mw >> bit) & 1u) ? 0.f : __expf(s[r] - mrow[r]);
      t += e;
    }
    // wave column total (16 rows): reduce over g groups
    t += __shfl_xor(t, 16);
    t += __shfl_xor(t, 32);
    if (g == 0) Tw[w][nt*16 + li] = t;
  }
  __syncthreads();
  const float s4 = Tw[0][tid&255] + Tw[1][tid&255] + Tw[2][tid&255] + Tw[3][tid&255];
  Tsum[(((size_t)bh * 16 + qc) << 10) + col0 + (tid & 255)] = s4;
}

// ---------- scan: exclusive prefix of Tsum over 16 chunks per (bh,col) ------
__global__ __launch_bounds__(256)
void scan_kernel(const float* __restrict__ Tsum, float* __restrict__ Cscan){
  const int bid = blockIdx.x;           // 256: bh(64) x colgroup(4)
  const int bh = bid >> 2, cg = bid & 3;
  const int col = cg * 256 + threadIdx.x;
  float run = 0.f;
  for (int qc = 0; qc < 16; ++qc){
    const size_t idx = (((size_t)bh * 16 + qc) << 10) + col;
    Cscan[idx] = run;
    run += Tsum[idx];
  }
}

// ---------- pass2: penalty + u + PV over all 4 col-blocks, write context ----
// grid = B*H * 16 chunks = 1024 WGs, 4 waves x 16 rows; 2 barriers per block.
__global__ __launch_bounds__(256)
void attn2_kernel(const u16* __restrict__ Qb, const u16* __restrict__ Kb,
                  const u16* __restrict__ Vb, const u32* __restrict__ bm,
                  const float* __restrict__ mbuf, const float* __restrict__ Cscan,
                  u16* __restrict__ ctxb)
{
  __shared__ alignas(16) u16 Vt[64][264];       // V^T for current col block
  __shared__ alignas(16) u16 Ulds[4][16][264];  // per-wave u rows (bf16)
  __shared__ float Tw[4][256];                  // per-wave column totals

  const int tid = threadIdx.x, l = tid & 63, w = tid >> 6;
  const int li = l & 15, g = l >> 4;
  const int bid = blockIdx.x;
  const int bh = bid >> 4, qc = bid & 15;
  const int b = bh >> 4, h = bh & 15;
  const int qrow0 = qc * 64 + w * 16;
  const u32* bmb = bm + ((size_t)b << 15);

  const u16* qbase = &Qb[((size_t)bh * 1024 + qrow0 + li) * 64 + g * 8];
  const v8bf a0 = *(const v8bf*)qbase;
  const v8bf a1 = *(const v8bf*)(qbase + 32);
  float mrow[4];
  #pragma unroll
  for (int r = 0; r < 4; ++r) mrow[r] = mbuf[(size_t)bh * 1024 + qrow0 + g*4 + r];

  v4f pv[4];
  #pragma unroll
  for (int n = 0; n < 4; ++n) pv[n] = (v4f){0.f,0.f,0.f,0.f};
  float rs[4] = {0.f, 0.f, 0.f, 0.f};

  for (int kb = 0; kb < 4; ++kb){
    const int col0 = kb * 256;
    if (kb) __syncthreads();                 // protect Vt/Tw reuse

    // stage V^T for this column block
    #pragma unroll
    for (int j = 0; j < 8; ++j){
      const int k = (tid >> 3) + j * 32;
      const int dv0 = (tid & 7) * 8;
      v8us vv = *(const v8us*)&Vb[((size_t)bh * 1024 + col0 + k) * 64 + dv0];
      #pragma unroll
      for (int i = 0; i < 8; ++i) Vt[dv0 + i][k] = vv[i];
    }

    // scores + exp for 16 rows x 256 cols
    v4f sc[16];
    float cg16[16];
    #pragma unroll
    for (int nt = 0; nt < 16; ++nt){
      const u16* kbase = &Kb[((size_t)bh * 1024 + col0 + nt*16 + li) * 64 + g * 8];
      v8bf b0 = *(const v8bf*)kbase;
      v8bf b1 = *(const v8bf*)(kbase + 32);
      v4f s = (v4f){0.f,0.f,0.f,0.f};
      s = __builtin_amdgcn_mfma_f32_16x16x32_bf16(a0, b0, s, 0, 0, 0);
      s = __builtin_amdgcn_mfma_f32_16x16x32_bf16(a1, b1, s, 0, 0, 0);
      const int wi = (col0 >> 5) + (nt >> 1);
      const int bit = ((nt & 1) << 4) + li;
      float t = 0.f;
      #pragma unroll
      for (int r = 0; r < 4; ++r){
        const int row = qrow0 + g*4 + r;
        const u32 mw = bmb[(row << 5) | wi];
        const float e = ((mw >> bit) & 1u) ? 0.f : __expf(s[r] - mrow[r]);
        s[r] = e;
        t += e;
      }
      sc[nt] = s;
      // exclusive carry over g-groups + wave total at g==3
      const float t1 = __shfl_up(t, 16);
      const float t2 = __shfl_up(t, 32);
      const float t3 = __shfl_up(t, 48);
      float c = 0.f;
      if (g >= 1) c += t1;
      if (g >= 2) c += t2;
      if (g >= 3) c += t3;
      cg16[nt] = c;
      if (g == 3) Tw[w][nt*16 + li] = c + t;
    }
    __syncthreads();                        // Vt staged + Tw ready

    // penalty -> u -> Ulds + rowsums
    #pragma unroll
    for (int nt = 0; nt < 16; ++nt){
      const int c = nt*16 + li;
      float base = Cscan[(((size_t)bh * 16 + qc) << 10) + col0 + c];
      if (w > 0) base += Tw[0][c];
      if (w > 1) base += Tw[1][c];
      if (w > 2) base += Tw[2][c];
      float run = 0.f;
      #pragma unroll
      for (int r = 0; r < 4; ++r){
        const int Rg = qrow0 + g*4 + r;
        float pen = base + cg16[nt] + run;
        if (Rg == 0) pen = 1.0f;
        const float e = sc[nt][r];
        const float u = e / (pen + 1e-8f);
        run += e;
        rs[r] += u;
        Ulds[w][g*4 + r][c] = f2b(u);
      }
    }

    // PV: (16 x 256) @ (256 x 64), per-wave buffers (no barrier needed)
    #pragma unroll
    for (int kk = 0; kk < 8; ++kk){
      v8bf ua = *(const v8bf*)&Ulds[w][li][g*8 + kk*32];
      #pragma unroll
      for (int n = 0; n < 4; ++n){
        v8bf vb = *(const v8bf*)&Vt[n*16 + li][g*8 + kk*32];
        pv[n] = __builtin_amdgcn_mfma_f32_16x16x32_bf16(ua, vb, pv[n], 0, 0, 0);
      }
    }
  }

  // total rowsums across all 1024 cols (reduce over li within group)
  #pragma unroll
  for (int r = 0; r < 4; ++r){
    float v = rs[r];
    v += __shfl_xor(v, 1);
    v += __shfl_xor(v, 2);
    v += __shfl_xor(v, 4);
    v += __shfl_xor(v, 8);
    rs[r] = v;
  }

  // write normalized context: ctxb[b][l][h*64+dv]
  #pragma unroll
  for (int n = 0; n < 4; ++n){
    #pragma unroll
    for (int r = 0; r < 4; ++r){
      const int lrow = qrow0 + g*4 + r;
      const int dv = n*16 + li;
      ctxb[(((size_t)b << 10) + lrow) * 1024 + h*64 + dv] = f2b(pv[n][r] / rs[r]);
    }
  }
}

extern "C" void kernel_launch(void* const* d_in, const int* in_sizes, int n_in,
                              void* d_out, int out_size, void* d_ws, size_t ws_size,
                              hipStream_t stream)
{
  const float* key   = (const float*)d_in[0];
  const float* value = (const float*)d_in[1];
  const float* query = (const float*)d_in[2];
  const void*  mask  = d_in[3];
  const float* Wq = (const float*)d_in[4];
  const float* bq = (const float*)d_in[5];
  const float* Wk = (const float*)d_in[6];
  const float* bk = (const float*)d_in[7];
  const float* Wv = (const float*)d_in[8];
  const float* bv = (const float*)d_in[9];
  const float* Wo = (const float*)d_in[10];
  const float* bo = (const float*)d_in[11];

  if (ws_size < (58ull << 20)) return;  // 57 MB used (guard matches r2 pass)

  char* ws = (char*)d_ws;
  u16*   Qb    = (u16*)(ws);
  u16*   Kb    = (u16*)(ws + (8ull  << 20));
  u16*   Vb    = (u16*)(ws + (16ull << 20));
  u16*   Ac    = (u16*)(ws + (24ull << 20));
  u16*   ctxb  = (u16*)(ws + (32ull << 20));
  u16*   Wtq   = (u16*)(ws + (40ull << 20));
  u16*   Wtk   = (u16*)(ws + (42ull << 20));
  u16*   Wtv   = (u16*)(ws + (44ull << 20));
  u16*   Wto   = (u16*)(ws + (46ull << 20));
  float* mbuf  = (float*)(ws + (48ull << 20));
  u32*   bmp   = (u32*)  (ws + (48ull << 20) + (256u << 10));
  int*   flag  = (int*)  (ws + (48ull << 20) + (768u << 10));
  float* Tsum  = (float*)(ws + (49ull << 20));
  float* Cscan = (float*)(ws + (53ull << 20));

  detect_kernel<<<1, 256, 0, stream>>>((const u32*)mask, flag);
  pack_mask<<<512, 256, 0, stream>>>(mask, flag, bmp);

  dim3 tg(16, 16);
  transpose_cast<<<tg, 256, 0, stream>>>(Wq, Wtq);
  transpose_cast<<<tg, 256, 0, stream>>>(Wk, Wtk);
  transpose_cast<<<tg, 256, 0, stream>>>(Wv, Wtv);
  transpose_cast<<<tg, 256, 0, stream>>>(Wo, Wto);

  dim3 gg(16, 32);
  cast_bf16<<<2048, 256, 0, stream>>>(query, Ac);
  gemm_bf16<0><<<gg, 256, 0, stream>>>(Ac, Wtq, bq, 0.125f, Qb);
  cast_bf16<<<2048, 256, 0, stream>>>(key, Ac);
  gemm_bf16<0><<<gg, 256, 0, stream>>>(Ac, Wtk, bk, 1.0f, Kb);
  cast_bf16<<<2048, 256, 0, stream>>>(value, Ac);
  gemm_bf16<0><<<gg, 256, 0, stream>>>(Ac, Wtv, bv, 1.0f, Vb);

  rowmax_kernel<<<1024, 256, 0, stream>>>(Qb, Kb, bmp, mbuf);
  colsum_kernel<<<4096, 256, 0, stream>>>(Qb, Kb, bmp, mbuf, Tsum);
  scan_kernel<<<256, 256, 0, stream>>>(Tsum, Cscan);
  attn2_kernel<<<1024, 256, 0, stream>>>(Qb, Kb, Vb, bmp, mbuf, Cscan, ctxb);

  gemm_bf16<1><<<gg, 256, 0, stream>>>(ctxb, Wto, bo, 1.0f, d_out);
}

// Round 5
// 499.640 us; speedup vs baseline: 1.6297x; 1.0837x over previous
//
#include <hip/hip_runtime.h>
#include <hip/hip_bf16.h>

// MultiHeadedAttention with coverage penalty, MI355X/gfx950.
// B=4 L=1024 D=1024 H=16 DK=DV=64. bf16 MFMA, fp32 accum; tol 3.58e-2.
//
// v4: attn2 KVBLK 256->128 (LDS 70.7->36.9 KB, 2->4 WG/CU) + rcp for divides;
// GEMM rebuilt m97-style: global_load_lds width=16, linear LDS, XOR-swizzled
// source addressing + swizzled ds_read (rule: linear dest + inv-swz source +
// swz read). Pipeline unchanged otherwise.
//
// ws layout (57 MB used; guard 58 MB known-good):
//   0M: Qb bf16[B*H][L][64] (Q/8) | 8M: Kb | 16M: Vb | 24M: Ac bf16[4096][1024]
//   32M: ctxb bf16[B][L][H*64] | 40M: Wt bf16 4x[1024][1024]
//   48M: mbuf f32[B*H*L] | 48.25M: bm u32[B][L][32] | 48.75M: flag
//   49M: Tsum f32[B*H][16][1024] | 53M: Cscan f32[B*H][16][1024]

typedef unsigned short u16;
typedef unsigned int u32;
typedef __bf16 v8bf __attribute__((ext_vector_type(8)));
typedef u16    v8us __attribute__((ext_vector_type(8)));
typedef float  v4f  __attribute__((ext_vector_type(4)));

__device__ __forceinline__ u16 f2b(float f){
  __hip_bfloat16 h = __float2bfloat16(f);
  return __builtin_bit_cast(u16, h);
}

// ---------- mask dtype detect (0=bool byte, 1=int32, 2=f32, 3=bf16) ----------
__global__ void detect_kernel(const u32* __restrict__ m, int* __restrict__ flag){
  __shared__ int sb1, sb3, snz;
  int tid = threadIdx.x;
  if (tid == 0){ sb1 = 0; sb3 = 0; snz = 0; }
  __syncthreads();
  int l1 = 0, l3 = 0, ln = 0;
  for (int i = tid; i < 65536; i += 256){
    u32 v = m[i];
    u32 b1 = (v >> 8) & 0xffu, b2 = (v >> 16) & 0xffu, b3 = (v >> 24) & 0xffu;
    l1 |= (b1 == 0x3fu);
    l3 |= (b3 == 0x3fu);
    ln |= ((b1 | b2 | b3) != 0u);
  }
  if (l1) atomicOr(&sb1, 1);
  if (l3) atomicOr(&sb3, 1);
  if (ln) atomicOr(&snz, 1);
  __syncthreads();
  if (tid == 0) *flag = sb1 ? 3 : (sb3 ? 2 : (snz ? 0 : 1));
}

// ---------- pack mask into bits: bm[(b*1024+row)*32 + w], bit = col&31 ------
__global__ __launch_bounds__(256)
void pack_mask(const void* __restrict__ m, const int* __restrict__ modep,
               u32* __restrict__ bm)
{
  const int w = blockIdx.x * 256 + threadIdx.x;
  const int mode = *modep;
  u32 out = 0;
  if (mode == 0){
    const u32* p = (const u32*)m + (size_t)w * 8;
    #pragma unroll
    for (int i = 0; i < 8; i++){
      u32 v = p[i];
      if (v & 0x000000ffu) out |= 1u << (4*i+0);
      if (v & 0x0000ff00u) out |= 1u << (4*i+1);
      if (v & 0x00ff0000u) out |= 1u << (4*i+2);
      if (v & 0xff000000u) out |= 1u << (4*i+3);
    }
  } else if (mode == 3){
    const u16* p = (const u16*)m + (size_t)w * 32;
    for (int i = 0; i < 32; i++) if (p[i]) out |= 1u << i;
  } else {
    const u32* p = (const u32*)m + (size_t)w * 32;
    for (int i = 0; i < 32; i++) if (p[i]) out |= 1u << i;
  }
  bm[w] = out;
}

// ---------- fp32 -> bf16 flat cast (vector8) --------------------------------
__global__ __launch_bounds__(256)
void cast_bf16(const float* __restrict__ in, u16* __restrict__ out){
  const int i = blockIdx.x * 256 + threadIdx.x;
  const float4* p = (const float4*)(in + (size_t)i * 8);
  float4 a = p[0], b = p[1];
  v8us r;
  r[0]=f2b(a.x); r[1]=f2b(a.y); r[2]=f2b(a.z); r[3]=f2b(a.w);
  r[4]=f2b(b.x); r[5]=f2b(b.y); r[6]=f2b(b.z); r[7]=f2b(b.w);
  ((v8us*)out)[i] = r;
}

// ---------- W [k][n] f32 -> Wt [n][k] bf16, 64x64 LDS tiles -----------------
__global__ __launch_bounds__(256)
void transpose_cast(const float* __restrict__ W, u16* __restrict__ Wt){
  __shared__ float T[64][65];
  const int ki = blockIdx.y, ni = blockIdx.x, t = threadIdx.x;
  const int r = t >> 2, c4 = (t & 3) * 16;
  const float4* src = (const float4*)&W[(size_t)(ki*64 + r) * 1024 + ni*64 + c4];
  #pragma unroll
  for (int i = 0; i < 4; i++){
    float4 f = src[i];
    T[r][c4+4*i+0]=f.x; T[r][c4+4*i+1]=f.y; T[r][c4+4*i+2]=f.z; T[r][c4+4*i+3]=f.w;
  }
  __syncthreads();
  u16* dst = &Wt[(size_t)(ni*64 + r) * 1024 + ki*64 + c4];
  v8us o0, o1;
  #pragma unroll
  for (int j = 0; j < 8; j++){ o0[j] = f2b(T[c4+j][r]); o1[j] = f2b(T[c4+8+j][r]); }
  *(v8us*)dst = o0;
  *(v8us*)(dst + 8) = o1;
}

// ---------- GEMM v4: A bf16[4096][1024] @ Wt^T + bias. 128x64 tile, BK=64 ---
// global_load_lds(16B) staging; LDS linear; XOR swizzle: phys 16B-slot c8
// holds logical c8^(r&7); ds_read applies the same XOR. OMODE as before.
template<int OMODE>
__global__ __launch_bounds__(256)
void gemm_gl(const u16* __restrict__ A, const u16* __restrict__ Wt,
             const float* __restrict__ bias, float scale, void* __restrict__ outp)
{
  __shared__ alignas(16) u16 As[128 * 64];   // [r][c8*8], swizzled slots
  __shared__ alignas(16) u16 Bs[64 * 64];
  const int tid = threadIdx.x, l = tid & 63, w = tid >> 6;
  const int li = l & 15, g = l >> 4;
  const int rowBase = blockIdx.y * 128, colBase = blockIdx.x * 64;
  const int wm = w >> 1, wn = w & 1;   // 2x2 wave grid; wave out 64x32

  v4f acc[4][2];
  #pragma unroll
  for (int i = 0; i < 4; i++)
    #pragma unroll
    for (int j = 0; j < 2; j++) acc[i][j] = (v4f){0.f,0.f,0.f,0.f};

  for (int kt = 0; kt < 16; ++kt){
    const int k0 = kt * 64;
    __syncthreads();
    // stage A: 1024 16B-slots; wave w, pass j covers slots j*256 + w*64 + lane
    #pragma unroll
    for (int j = 0; j < 4; ++j){
      const int s = j * 256 + tid;
      const int r = s >> 3, c8 = s & 7;
      const int c8s = c8 ^ (r & 7);
      const u16* src = &A[(size_t)(rowBase + r) * 1024 + k0 + c8s * 8];
      __builtin_amdgcn_global_load_lds(
        (const __attribute__((address_space(1))) void*)src,
        (__attribute__((address_space(3))) void*)(As + (size_t)(j*256 + w*64) * 8),
        16, 0, 0);
    }
    // stage B: 512 slots
    #pragma unroll
    for (int j = 0; j < 2; ++j){
      const int s = j * 256 + tid;
      const int r = s >> 3, c8 = s & 7;
      const int c8s = c8 ^ (r & 7);
      const u16* src = &Wt[(size_t)(colBase + r) * 1024 + k0 + c8s * 8];
      __builtin_amdgcn_global_load_lds(
        (const __attribute__((address_space(1))) void*)src,
        (__attribute__((address_space(3))) void*)(Bs + (size_t)(j*256 + w*64) * 8),
        16, 0, 0);
    }
    __syncthreads();
    #pragma unroll
    for (int kk = 0; kk < 2; ++kk){
      v8bf af[4], bf[2];
      #pragma unroll
      for (int mt = 0; mt < 4; ++mt){
        const int r = wm*64 + mt*16 + li;
        af[mt] = *(const v8bf*)&As[r*64 + (((kk*4 + g) ^ (r & 7)) * 8)];
      }
      #pragma unroll
      for (int nt = 0; nt < 2; ++nt){
        const int c = wn*32 + nt*16 + li;
        bf[nt] = *(const v8bf*)&Bs[c*64 + (((kk*4 + g) ^ (c & 7)) * 8)];
      }
      #pragma unroll
      for (int mt = 0; mt < 4; ++mt)
        #pragma unroll
        for (int nt = 0; nt < 2; ++nt)
          acc[mt][nt] = __builtin_amdgcn_mfma_f32_16x16x32_bf16(af[mt], bf[nt], acc[mt][nt], 0, 0, 0);
    }
  }

  #pragma unroll
  for (int mt = 0; mt < 4; ++mt){
    #pragma unroll
    for (int nt = 0; nt < 2; ++nt){
      const int gc = colBase + wn*32 + nt*16 + li;
      const float bs = bias[gc];
      #pragma unroll
      for (int r = 0; r < 4; ++r){
        const int gr = rowBase + wm*64 + mt*16 + g*4 + r;
        float v = acc[mt][nt][r] + bs;
        if (OMODE == 0){
          v *= scale;
          const int bb = gr >> 10, lp = gr & 1023;
          const int h = gc >> 6, dk = gc & 63;
          ((u16*)outp)[((((size_t)bb*16 + h) << 10) + lp) * 64 + dk] = f2b(v);
        } else {
          ((float*)outp)[(size_t)gr * 1024 + gc] = v;
        }
      }
    }
  }
}

// ---------- row maxes of masked scores. grid B*H*16, 4 waves x 16 rows ------
__global__ __launch_bounds__(256)
void rowmax_kernel(const u16* __restrict__ Qb, const u16* __restrict__ Kb,
                   const u32* __restrict__ bm, float* __restrict__ mbuf)
{
  const int tid = threadIdx.x, l = tid & 63, w = tid >> 6;
  const int li = l & 15, g = l >> 4;
  const int bid = blockIdx.x;
  const int bh = bid >> 4, qb = bid & 15;
  const int b = bh >> 4;
  const int qrow0 = qb * 64 + w * 16;
  const u32* bmb = bm + ((size_t)b << 15);

  const u16* qbase = &Qb[((size_t)bh * 1024 + qrow0 + li) * 64 + g * 8];
  const v8bf a0 = *(const v8bf*)qbase;
  const v8bf a1 = *(const v8bf*)(qbase + 32);

  float rm[4] = {-3.0e38f, -3.0e38f, -3.0e38f, -3.0e38f};

  for (int kt = 0; kt < 64; ++kt){
    const u16* kbase = &Kb[((size_t)bh * 1024 + kt*16 + li) * 64 + g * 8];
    v8bf b0 = *(const v8bf*)kbase;
    v8bf b1 = *(const v8bf*)(kbase + 32);
    v4f s = (v4f){0.f,0.f,0.f,0.f};
    s = __builtin_amdgcn_mfma_f32_16x16x32_bf16(a0, b0, s, 0, 0, 0);
    s = __builtin_amdgcn_mfma_f32_16x16x32_bf16(a1, b1, s, 0, 0, 0);
    const int bit = ((kt & 1) << 4) + li;
    #pragma unroll
    for (int r = 0; r < 4; ++r){
      const int row = qrow0 + g*4 + r;
      const u32 mw = bmb[(row << 5) | (kt >> 1)];
      const float sv = ((mw >> bit) & 1u) ? -1e18f : s[r];
      rm[r] = fmaxf(rm[r], sv);
    }
  }
  #pragma unroll
  for (int r = 0; r < 4; ++r){
    float v = rm[r];
    v = fmaxf(v, __shfl_xor(v, 1));
    v = fmaxf(v, __shfl_xor(v, 2));
    v = fmaxf(v, __shfl_xor(v, 4));
    v = fmaxf(v, __shfl_xor(v, 8));
    rm[r] = v;
  }
  if (li == 0){
    #pragma unroll
    for (int r = 0; r < 4; ++r)
      mbuf[(size_t)bh * 1024 + qrow0 + g*4 + r] = rm[r];
  }
}

// ---------- pass1: per-chunk (64 rows) column sums of e ---------------------
// grid = B*H * 16 chunks * 4 colblocks = 4096 WGs, 4 waves x 16 rows.
__global__ __launch_bounds__(256)
void colsum_kernel(const u16* __restrict__ Qb, const u16* __restrict__ Kb,
                   const u32* __restrict__ bm, const float* __restrict__ mbuf,
                   float* __restrict__ Tsum)
{
  __shared__ float Tw[4][256];
  const int tid = threadIdx.x, l = tid & 63, w = tid >> 6;
  const int li = l & 15, g = l >> 4;
  const int bid = blockIdx.x;
  const int bh = bid >> 6, qc = (bid >> 2) & 15, kb = bid & 3;
  const int b = bh >> 4;
  const int col0 = kb * 256;
  const int qrow0 = qc * 64 + w * 16;
  const u32* bmb = bm + ((size_t)b << 15);

  const u16* qbase = &Qb[((size_t)bh * 1024 + qrow0 + li) * 64 + g * 8];
  const v8bf a0 = *(const v8bf*)qbase;
  const v8bf a1 = *(const v8bf*)(qbase + 32);
  float mrow[4];
  #pragma unroll
  for (int r = 0; r < 4; ++r) mrow[r] = mbuf[(size_t)bh * 1024 + qrow0 + g*4 + r];

  #pragma unroll
  for (int nt = 0; nt < 16; ++nt){
    const u16* kbase = &Kb[((size_t)bh * 1024 + col0 + nt*16 + li) * 64 + g * 8];
    v8bf b0 = *(const v8bf*)kbase;
    v8bf b1 = *(const v8bf*)(kbase + 32);
    v4f s = (v4f){0.f,0.f,0.f,0.f};
    s = __builtin_amdgcn_mfma_f32_16x16x32_bf16(a0, b0, s, 0, 0, 0);
    s = __builtin_amdgcn_mfma_f32_16x16x32_bf16(a1, b1, s, 0, 0, 0);
    const int wi = (col0 >> 5) + (nt >> 1);
    const int bit = ((nt & 1) << 4) + li;
    float t = 0.f;
    #pragma unroll
    for (int r = 0; r < 4; ++r){
      const int row = qrow0 + g*4 + r;
      const u32 mw = bmb[(row << 5) | wi];
      const float e = ((mw >> bit) & 1u) ? 0.f : __expf(s[r] - mrow[r]);
      t += e;
    }
    t += __shfl_xor(t, 16);
    t += __shfl_xor(t, 32);
    if (g == 0) Tw[w][nt*16 + li] = t;
  }
  __syncthreads();
  const float s4 = Tw[0][tid&255] + Tw[1][tid&255] + Tw[2][tid&255] + Tw[3][tid&255];
  Tsum[(((size_t)bh * 16 + qc) << 10) + col0 + (tid & 255)] = s4;
}

// ---------- scan: exclusive prefix of Tsum over 16 chunks per (bh,col) ------
__global__ __launch_bounds__(256)
void scan_kernel(const float* __restrict__ Tsum, float* __restrict__ Cscan){
  const int bid = blockIdx.x;           // 256: bh(64) x colgroup(4)
  const int bh = bid >> 2, cg = bid & 3;
  const int col = cg * 256 + threadIdx.x;
  float run = 0.f;
  for (int qc = 0; qc < 16; ++qc){
    const size_t idx = (((size_t)bh * 16 + qc) << 10) + col;
    Cscan[idx] = run;
    run += Tsum[idx];
  }
}

// ---------- pass2: penalty + u + PV over 8 col-blocks of 128 ----------------
// grid = B*H*16 = 1024 WGs, 4 waves x 16 rows; LDS 36.9 KB -> 4 WG/CU.
__global__ __launch_bounds__(256, 4)
void attn2_kernel(const u16* __restrict__ Qb, const u16* __restrict__ Kb,
                  const u16* __restrict__ Vb, const u32* __restrict__ bm,
                  const float* __restrict__ mbuf, const float* __restrict__ Cscan,
                  u16* __restrict__ ctxb)
{
  __shared__ alignas(16) u16 Vt[64][136];       // V^T for current 128-col block
  __shared__ alignas(16) u16 Ulds[4][16][136];  // per-wave u rows (bf16)
  __shared__ float Tw[4][128];                  // per-wave column totals

  const int tid = threadIdx.x, l = tid & 63, w = tid >> 6;
  const int li = l & 15, g = l >> 4;
  const int bid = blockIdx.x;
  const int bh = bid >> 4, qc = bid & 15;
  const int b = bh >> 4, h = bh & 15;
  const int qrow0 = qc * 64 + w * 16;
  const u32* bmb = bm + ((size_t)b << 15);

  const u16* qbase = &Qb[((size_t)bh * 1024 + qrow0 + li) * 64 + g * 8];
  const v8bf a0 = *(const v8bf*)qbase;
  const v8bf a1 = *(const v8bf*)(qbase + 32);
  float mrow[4];
  #pragma unroll
  for (int r = 0; r < 4; ++r) mrow[r] = mbuf[(size_t)bh * 1024 + qrow0 + g*4 + r];

  v4f pv[4];
  #pragma unroll
  for (int n = 0; n < 4; ++n) pv[n] = (v4f){0.f,0.f,0.f,0.f};
  float rs[4] = {0.f, 0.f, 0.f, 0.f};

  for (int kb = 0; kb < 8; ++kb){
    const int col0 = kb * 128;
    if (kb) __syncthreads();                 // protect Vt/Tw reuse

    // stage V^T: 128 k x 64 dv, 4 v8us per thread
    #pragma unroll
    for (int j = 0; j < 4; ++j){
      const int k = (tid >> 3) + j * 32;
      const int dv0 = (tid & 7) * 8;
      v8us vv = *(const v8us*)&Vb[((size_t)bh * 1024 + col0 + k) * 64 + dv0];
      #pragma unroll
      for (int i = 0; i < 8; ++i) Vt[dv0 + i][k] = vv[i];
    }

    // scores + exp for 16 rows x 128 cols
    v4f sc[8];
    float cg16[8];
    #pragma unroll
    for (int nt = 0; nt < 8; ++nt){
      const u16* kbase = &Kb[((size_t)bh * 1024 + col0 + nt*16 + li) * 64 + g * 8];
      v8bf b0 = *(const v8bf*)kbase;
      v8bf b1 = *(const v8bf*)(kbase + 32);
      v4f s = (v4f){0.f,0.f,0.f,0.f};
      s = __builtin_amdgcn_mfma_f32_16x16x32_bf16(a0, b0, s, 0, 0, 0);
      s = __builtin_amdgcn_mfma_f32_16x16x32_bf16(a1, b1, s, 0, 0, 0);
      const int wi = (col0 >> 5) + (nt >> 1);
      const int bit = ((nt & 1) << 4) + li;
      float t = 0.f;
      #pragma unroll
      for (int r = 0; r < 4; ++r){
        const int row = qrow0 + g*4 + r;
        const u32 mw = bmb[(row << 5) | wi];
        const float e = ((mw >> bit) & 1u) ? 0.f : __expf(s[r] - mrow[r]);
        s[r] = e;
        t += e;
      }
      sc[nt] = s;
      const float t1 = __shfl_up(t, 16);
      const float t2 = __shfl_up(t, 32);
      const float t3 = __shfl_up(t, 48);
      float c = 0.f;
      if (g >= 1) c += t1;
      if (g >= 2) c += t2;
      if (g >= 3) c += t3;
      cg16[nt] = c;
      if (g == 3) Tw[w][nt*16 + li] = c + t;
    }
    __syncthreads();                        // Vt staged + Tw ready

    // penalty -> u -> Ulds + rowsums (u = e * rcp(pen))
    #pragma unroll
    for (int nt = 0; nt < 8; ++nt){
      const int c = nt*16 + li;
      float base = Cscan[(((size_t)bh * 16 + qc) << 10) + col0 + c];
      if (w > 0) base += Tw[0][c];
      if (w > 1) base += Tw[1][c];
      if (w > 2) base += Tw[2][c];
      float run = 0.f;
      #pragma unroll
      for (int r = 0; r < 4; ++r){
        const int Rg = qrow0 + g*4 + r;
        float pen = base + cg16[nt] + run;
        if (Rg == 0) pen = 1.0f;
        const float e = sc[nt][r];
        const float u = e * __builtin_amdgcn_rcpf(pen + 1e-8f);
        run += e;
        rs[r] += u;
        Ulds[w][g*4 + r][c] = f2b(u);
      }
    }

    // PV: (16 x 128) @ (128 x 64), per-wave buffers
    #pragma unroll
    for (int kk = 0; kk < 4; ++kk){
      v8bf ua = *(const v8bf*)&Ulds[w][li][g*8 + kk*32];
      #pragma unroll
      for (int n = 0; n < 4; ++n){
        v8bf vb = *(const v8bf*)&Vt[n*16 + li][g*8 + kk*32];
        pv[n] = __builtin_amdgcn_mfma_f32_16x16x32_bf16(ua, vb, pv[n], 0, 0, 0);
      }
    }
  }

  #pragma unroll
  for (int r = 0; r < 4; ++r){
    float v = rs[r];
    v += __shfl_xor(v, 1);
    v += __shfl_xor(v, 2);
    v += __shfl_xor(v, 4);
    v += __shfl_xor(v, 8);
    rs[r] = v;
  }

  #pragma unroll
  for (int n = 0; n < 4; ++n){
    #pragma unroll
    for (int r = 0; r < 4; ++r){
      const int lrow = qrow0 + g*4 + r;
      const int dv = n*16 + li;
      ctxb[(((size_t)b << 10) + lrow) * 1024 + h*64 + dv] = f2b(pv[n][r] / rs[r]);
    }
  }
}

extern "C" void kernel_launch(void* const* d_in, const int* in_sizes, int n_in,
                              void* d_out, int out_size, void* d_ws, size_t ws_size,
                              hipStream_t stream)
{
  const float* key   = (const float*)d_in[0];
  const float* value = (const float*)d_in[1];
  const float* query = (const float*)d_in[2];
  const void*  mask  = d_in[3];
  const float* Wq = (const float*)d_in[4];
  const float* bq = (const float*)d_in[5];
  const float* Wk = (const float*)d_in[6];
  const float* bk = (const float*)d_in[7];
  const float* Wv = (const float*)d_in[8];
  const float* bv = (const float*)d_in[9];
  const float* Wo = (const float*)d_in[10];
  const float* bo = (const float*)d_in[11];

  if (ws_size < (58ull << 20)) return;

  char* ws = (char*)d_ws;
  u16*   Qb    = (u16*)(ws);
  u16*   Kb    = (u16*)(ws + (8ull  << 20));
  u16*   Vb    = (u16*)(ws + (16ull << 20));
  u16*   Ac    = (u16*)(ws + (24ull << 20));
  u16*   ctxb  = (u16*)(ws + (32ull << 20));
  u16*   Wtq   = (u16*)(ws + (40ull << 20));
  u16*   Wtk   = (u16*)(ws + (42ull << 20));
  u16*   Wtv   = (u16*)(ws + (44ull << 20));
  u16*   Wto   = (u16*)(ws + (46ull << 20));
  float* mbuf  = (float*)(ws + (48ull << 20));
  u32*   bmp   = (u32*)  (ws + (48ull << 20) + (256u << 10));
  int*   flag  = (int*)  (ws + (48ull << 20) + (768u << 10));
  float* Tsum  = (float*)(ws + (49ull << 20));
  float* Cscan = (float*)(ws + (53ull << 20));

  detect_kernel<<<1, 256, 0, stream>>>((const u32*)mask, flag);
  pack_mask<<<512, 256, 0, stream>>>(mask, flag, bmp);

  dim3 tg(16, 16);
  transpose_cast<<<tg, 256, 0, stream>>>(Wq, Wtq);
  transpose_cast<<<tg, 256, 0, stream>>>(Wk, Wtk);
  transpose_cast<<<tg, 256, 0, stream>>>(Wv, Wtv);
  transpose_cast<<<tg, 256, 0, stream>>>(Wo, Wto);

  dim3 gg(16, 32);
  cast_bf16<<<2048, 256, 0, stream>>>(query, Ac);
  gemm_gl<0><<<gg, 256, 0, stream>>>(Ac, Wtq, bq, 0.125f, Qb);
  cast_bf16<<<2048, 256, 0, stream>>>(key, Ac);
  gemm_gl<0><<<gg, 256, 0, stream>>>(Ac, Wtk, bk, 1.0f, Kb);
  cast_bf16<<<2048, 256, 0, stream>>>(value, Ac);
  gemm_gl<0><<<gg, 256, 0, stream>>>(Ac, Wtv, bv, 1.0f, Vb);

  rowmax_kernel<<<1024, 256, 0, stream>>>(Qb, Kb, bmp, mbuf);
  colsum_kernel<<<4096, 256, 0, stream>>>(Qb, Kb, bmp, mbuf, Tsum);
  scan_kernel<<<256, 256, 0, stream>>>(Tsum, Cscan);
  attn2_kernel<<<1024, 256, 0, stream>>>(Qb, Kb, Vb, bmp, mbuf, Cscan, ctxb);

  gemm_gl<1><<<gg, 256, 0, stream>>>(ctxb, Wto, bo, 1.0f, d_out);
}